// Round 2
// baseline (18963.162 us; speedup 1.0000x reference)
//
#include <hip/hip_runtime.h>
#include <hip/hip_bf16.h>
#include <math.h>

#define Bb 8
#define Ss 4096
#define Hh 512
#define Ii 1024
#define Ee 8
#define NTOK (Bb*Ss)      // 32768 tokens
#define TT 32             // tokens per expert-block tile
#define IC 128            // I-chunk width
#define KS 16             // K slice for LDS staging
#define NBUCKET 64        // spread buckets for prob-sum atomics

// ws layout (bytes):
//   [0,32)            int   cnt[8]
//   [64, 64+2048)     float probs_part[NBUCKET][8]
//   [4096, +1MB)      int   ttok[E*NTOK]
//   [4096+1MB, +1MB)  float twt [E*NTOK]

#define FMA4(acc, s, b) { (acc).x += (s)*(b).x; (acc).y += (s)*(b).y; (acc).z += (s)*(b).z; (acc).w += (s)*(b).w; }

__device__ __forceinline__ float silu_f(float g) {
    return g / (1.0f + expf(-g));
}

// ---------------- Router ----------------
// One wave per token. Logits via LDS-cached w_router, butterfly reduce,
// top-2 (strict > keeps first index on ties, matching lax.top_k), softmax
// weights, append to per-expert token lists. Prob sums spread over buckets.
__global__ __launch_bounds__(256) void router_kernel(
    const float* __restrict__ hs, const float* __restrict__ wr,
    int* __restrict__ cnt, float* __restrict__ probs_part,
    int* __restrict__ ttok, float* __restrict__ twt)
{
    __shared__ __align__(16) float swr[Ee*Hh];   // 16KB
    __shared__ float sblk[Ee];
    int tid = threadIdx.x;
    for (int q = tid; q < Ee*Hh/4; q += 256)
        ((float4*)swr)[q] = ((const float4*)wr)[q];
    if (tid < Ee) sblk[tid] = 0.0f;
    __syncthreads();

    int lane = tid & 63;
    int t = blockIdx.x*4 + (tid >> 6);
    const float4* h4 = (const float4*)(hs + (size_t)t*Hh);

    float acc[Ee];
    #pragma unroll
    for (int e = 0; e < Ee; e++) acc[e] = 0.0f;
    #pragma unroll
    for (int r = 0; r < 2; r++) {
        float4 hv = h4[lane + 64*r];
        #pragma unroll
        for (int e = 0; e < Ee; e++) {
            float4 wv = ((const float4*)swr)[e*(Hh/4) + lane + 64*r];
            acc[e] += hv.x*wv.x + hv.y*wv.y + hv.z*wv.z + hv.w*wv.w;
        }
    }
    #pragma unroll
    for (int e = 0; e < Ee; e++) {
        #pragma unroll
        for (int off = 32; off > 0; off >>= 1)
            acc[e] += __shfl_xor(acc[e], off);
    }

    if (lane == 0) {
        // full softmax for aux probs
        float m = acc[0];
        #pragma unroll
        for (int e = 1; e < Ee; e++) m = fmaxf(m, acc[e]);
        float p[Ee], s = 0.0f;
        #pragma unroll
        for (int e = 0; e < Ee; e++) { p[e] = expf(acc[e]-m); s += p[e]; }
        float inv = 1.0f/s;
        #pragma unroll
        for (int e = 0; e < Ee; e++) atomicAdd(&sblk[e], p[e]*inv);

        // top-2
        int e0 = 0; float v0 = acc[0];
        #pragma unroll
        for (int e = 1; e < Ee; e++) if (acc[e] > v0) { v0 = acc[e]; e0 = e; }
        int e1 = -1; float v1 = -1e30f;
        #pragma unroll
        for (int e = 0; e < Ee; e++) if (e != e0 && acc[e] > v1) { v1 = acc[e]; e1 = e; }
        float r1 = expf(v1 - v0);
        float w0 = 1.0f/(1.0f + r1);
        float w1 = r1*w0;
        int p0 = atomicAdd(&cnt[e0], 1);
        ttok[e0*NTOK + p0] = t; twt[e0*NTOK + p0] = w0;
        int p1 = atomicAdd(&cnt[e1], 1);
        ttok[e1*NTOK + p1] = t; twt[e1*NTOK + p1] = w1;
    }
    __syncthreads();
    if (tid < Ee)
        atomicAdd(&probs_part[(blockIdx.x & (NBUCKET-1))*Ee + tid], sblk[tid]);
}

// ---------------- Aux loss ----------------
__global__ void aux_kernel(const int* __restrict__ cnt,
                           const float* __restrict__ probs_part,
                           float* __restrict__ out_aux)
{
    if (threadIdx.x == 0 && blockIdx.x == 0) {
        float aux = 0.0f;
        for (int e = 0; e < Ee; e++) {
            float ps = 0.0f;
            for (int b = 0; b < NBUCKET; b++) ps += probs_part[b*Ee + e];
            aux += (ps/(float)NTOK) * ((float)cnt[e]/(float)(2*NTOK));
        }
        out_aux[0] = aux * (float)Ee;
    }
}

// ---------------- Fused expert FFN ----------------
// 1-D grid, e = wgid&7: under round-robin XCD dispatch each XCD serves ONE
// expert, so that expert's ~6MB weights stay L2-resident (per-chunk slice
// ~768KB << 4MB). Block = 32-token tile of that expert's routed list.
// Per I-chunk of 128:
//   phase1: act[i][t] = silu(h@Wg^T) * (h@Wu^T)   (K=512, 16-k reg->LDS pipeline)
//   phase2: out[t][h] += act @ Wd^T slice          (acc in regs across chunks)
// Register prefetch pipeline per slice: write regs(s)->LDS; barrier;
// issue loads(s+1); FMA(s); barrier.
__global__ __launch_bounds__(256, 3) void expert_kernel(
    const float* __restrict__ hs,
    const float* __restrict__ wg, const float* __restrict__ wu,
    const float* __restrict__ wd,
    const int* __restrict__ cnt, const int* __restrict__ ttok,
    const float* __restrict__ twt,
    float* __restrict__ out)
{
    int e  = blockIdx.x & (Ee-1);      // XCD-aligned expert id
    int bx = blockIdx.x >> 3;          // tile index within expert
    int n = cnt[e];
    int j0 = bx * TT;
    if (j0 >= n) return;

    __shared__ __align__(16) float smem[IC*TT + KS*Hh];  // 16KB act + 32KB stage
    __shared__ int   sm_tok[TT];
    __shared__ float sm_wt[TT];
    float* sm_act = smem;                 // [IC][TT]
    float* sm_hT  = smem + IC*TT;         // [KS][TT]   (phase1, aliases stage)
    float* sm_wgT = smem + IC*TT + KS*TT; // [KS][IC]
    float* sm_wuT = smem + IC*TT + KS*TT + KS*IC; // [KS][IC]
    float* sm_wdT = smem + IC*TT;         // [KS][Hh]   (phase2, aliases stage)

    int tid = threadIdx.x;
    if (tid < TT) {
        int j = j0 + tid;
        int tk; float w;
        if (j < n) { tk = ttok[e*NTOK + j]; w = twt[e*NTOK + j]; }
        else       { tk = ttok[e*NTOK + j0]; w = 0.0f; }   // padded row: weight 0
        sm_tok[tid] = tk; sm_wt[tid] = w;
    }
    __syncthreads();

    const float* wg_e = wg + (size_t)e*Ii*Hh;
    const float* wu_e = wu + (size_t)e*Ii*Hh;
    const float* wd_e = wd + (size_t)e*Hh*Ii;

    int t0 = (tid >> 5) * 4;   // token sub-row, 0..28
    int x0 = (tid & 31) * 4;   // phase1: i base; phase2: h base

    // ---- hoisted staging addresses (constant across chunks/slices) ----
    // phase1 h^T staging (threads 0..127)
    int t_h = (tid >> 2) & (TT-1);
    int kq  = (tid & 3) << 2;
    const float* hrow_base = hs + (size_t)sm_tok[t_h]*Hh + kq;
    float* sm_hT_st = sm_hT + kq*TT + t_h;           // +c*TT for c=0..3
    // phase1 weight staging (all 256 threads)
    int il = tid & 127;
    int kb = (tid >> 7) << 3;                        // 0 or 8
    float* sm_wgT_st = sm_wgT + kb*IC + il;          // +c*IC
    float* sm_wuT_st = sm_wuT + kb*IC + il;
    // phase2 wd staging
    int hh = tid << 1;
    const float* wd_row0 = wd_e + (size_t)hh*Ii;
    const float* wd_row1 = wd_row0 + Ii;
    float* sm_wdT_st = sm_wdT + hh;                  // +k*Hh (+1 for rr=1)

    float4 acc_out[4][4];      // [tj][j]: h = x0 + 128*j + c  (64 regs, persists)
    #pragma unroll
    for (int a = 0; a < 4; a++)
        #pragma unroll
        for (int b = 0; b < 4; b++)
            acc_out[a][b] = make_float4(0.f, 0.f, 0.f, 0.f);

    for (int ic = 0; ic < Ii; ic += IC) {
        // ---------- phase 1: gate & up ----------
        float4 accg[4], accu[4];
        #pragma unroll
        for (int a = 0; a < 4; a++) { accg[a] = make_float4(0,0,0,0); accu[a] = make_float4(0,0,0,0); }

        const float* hp = hrow_base;
        const float* gp = wg_e + (size_t)(ic + il)*Hh + kb;
        const float* up = wu_e + (size_t)(ic + il)*Hh + kb;

        // prologue: load slice 0 into regs
        float4 hv = make_float4(0,0,0,0), g0, g1, u0, u1;
        if (tid < 128) hv = *(const float4*)hp;
        g0 = *(const float4*)gp;       g1 = *(const float4*)(gp + 4);
        u0 = *(const float4*)up;       u1 = *(const float4*)(up + 4);

        for (int ks = 0; ks < Hh; ks += KS) {
            // write current slice regs -> LDS
            if (tid < 128) {
                sm_hT_st[0*TT] = hv.x; sm_hT_st[1*TT] = hv.y;
                sm_hT_st[2*TT] = hv.z; sm_hT_st[3*TT] = hv.w;
            }
            sm_wgT_st[0*IC] = g0.x; sm_wgT_st[1*IC] = g0.y;
            sm_wgT_st[2*IC] = g0.z; sm_wgT_st[3*IC] = g0.w;
            sm_wgT_st[4*IC] = g1.x; sm_wgT_st[5*IC] = g1.y;
            sm_wgT_st[6*IC] = g1.z; sm_wgT_st[7*IC] = g1.w;
            sm_wuT_st[0*IC] = u0.x; sm_wuT_st[1*IC] = u0.y;
            sm_wuT_st[2*IC] = u0.z; sm_wuT_st[3*IC] = u0.w;
            sm_wuT_st[4*IC] = u1.x; sm_wuT_st[5*IC] = u1.y;
            sm_wuT_st[6*IC] = u1.z; sm_wuT_st[7*IC] = u1.w;
            __syncthreads();

            // prefetch next slice (overlaps FMA below)
            if (ks + KS < Hh) {
                hp += KS; gp += KS; up += KS;
                if (tid < 128) hv = *(const float4*)hp;
                g0 = *(const float4*)gp;   g1 = *(const float4*)(gp + 4);
                u0 = *(const float4*)up;   u1 = *(const float4*)(up + 4);
            }

            #pragma unroll
            for (int k = 0; k < KS; k++) {
                float4 a  = *(const float4*)&sm_hT [k*TT + t0];
                float4 bg = *(const float4*)&sm_wgT[k*IC + x0];
                float4 bu = *(const float4*)&sm_wuT[k*IC + x0];
                FMA4(accg[0], a.x, bg); FMA4(accg[1], a.y, bg);
                FMA4(accg[2], a.z, bg); FMA4(accg[3], a.w, bg);
                FMA4(accu[0], a.x, bu); FMA4(accu[1], a.y, bu);
                FMA4(accu[2], a.z, bu); FMA4(accu[3], a.w, bu);
            }
            __syncthreads();
        }

        // silu(g)*u -> sm_act[i][t]  (b128 stores over t)
        {
            float4 v;
            v.x = silu_f(accg[0].x)*accu[0].x; v.y = silu_f(accg[1].x)*accu[1].x;
            v.z = silu_f(accg[2].x)*accu[2].x; v.w = silu_f(accg[3].x)*accu[3].x;
            *(float4*)&sm_act[(x0+0)*TT + t0] = v;
            v.x = silu_f(accg[0].y)*accu[0].y; v.y = silu_f(accg[1].y)*accu[1].y;
            v.z = silu_f(accg[2].y)*accu[2].y; v.w = silu_f(accg[3].y)*accu[3].y;
            *(float4*)&sm_act[(x0+1)*TT + t0] = v;
            v.x = silu_f(accg[0].z)*accu[0].z; v.y = silu_f(accg[1].z)*accu[1].z;
            v.z = silu_f(accg[2].z)*accu[2].z; v.w = silu_f(accg[3].z)*accu[3].z;
            *(float4*)&sm_act[(x0+2)*TT + t0] = v;
            v.x = silu_f(accg[0].w)*accu[0].w; v.y = silu_f(accg[1].w)*accu[1].w;
            v.z = silu_f(accg[2].w)*accu[2].w; v.w = silu_f(accg[3].w)*accu[3].w;
            *(float4*)&sm_act[(x0+3)*TT + t0] = v;
        }
        __syncthreads();

        // ---------- phase 2: down proj ----------
        // prologue: load slice 0 (2 rows x 16 consecutive i)
        float4 c0[2][4];
        {
            const float* s0 = wd_row0 + ic;
            const float* s1 = wd_row1 + ic;
            #pragma unroll
            for (int q = 0; q < 4; q++) {
                c0[0][q] = *(const float4*)(s0 + 4*q);
                c0[1][q] = *(const float4*)(s1 + 4*q);
            }
        }
        for (int ks2 = 0; ks2 < IC; ks2 += KS) {
            // write current slice regs -> LDS transposed [16k][512h]
            #pragma unroll
            for (int rr = 0; rr < 2; rr++) {
                float* st = sm_wdT_st + rr;
                st[ 0*Hh] = c0[rr][0].x; st[ 1*Hh] = c0[rr][0].y;
                st[ 2*Hh] = c0[rr][0].z; st[ 3*Hh] = c0[rr][0].w;
                st[ 4*Hh] = c0[rr][1].x; st[ 5*Hh] = c0[rr][1].y;
                st[ 6*Hh] = c0[rr][1].z; st[ 7*Hh] = c0[rr][1].w;
                st[ 8*Hh] = c0[rr][2].x; st[ 9*Hh] = c0[rr][2].y;
                st[10*Hh] = c0[rr][2].z; st[11*Hh] = c0[rr][2].w;
                st[12*Hh] = c0[rr][3].x; st[13*Hh] = c0[rr][3].y;
                st[14*Hh] = c0[rr][3].z; st[15*Hh] = c0[rr][3].w;
            }
            __syncthreads();

            // prefetch next slice
            if (ks2 + KS < IC) {
                const float* s0 = wd_row0 + ic + ks2 + KS;
                const float* s1 = wd_row1 + ic + ks2 + KS;
                #pragma unroll
                for (int q = 0; q < 4; q++) {
                    c0[0][q] = *(const float4*)(s0 + 4*q);
                    c0[1][q] = *(const float4*)(s1 + 4*q);
                }
            }

            #pragma unroll
            for (int k = 0; k < KS; k++) {
                float4 av = *(const float4*)&sm_act[(ks2+k)*TT + t0];
                #pragma unroll
                for (int j = 0; j < 4; j++) {
                    float4 b = *(const float4*)&sm_wdT[k*Hh + x0 + 128*j];
                    FMA4(acc_out[0][j], av.x, b);
                    FMA4(acc_out[1][j], av.y, b);
                    FMA4(acc_out[2][j], av.z, b);
                    FMA4(acc_out[3][j], av.w, b);
                }
            }
            __syncthreads();
        }
    }

    // ---------- weighted scatter ----------
    #pragma unroll
    for (int tj = 0; tj < 4; tj++) {
        float w = sm_wt[t0 + tj];
        size_t base = (size_t)sm_tok[t0 + tj]*Hh;
        #pragma unroll
        for (int j = 0; j < 4; j++) {
            float4 v = acc_out[tj][j];
            atomicAdd(&out[base + x0 + 128*j + 0], v.x*w);
            atomicAdd(&out[base + x0 + 128*j + 1], v.y*w);
            atomicAdd(&out[base + x0 + 128*j + 2], v.z*w);
            atomicAdd(&out[base + x0 + 128*j + 3], v.w*w);
        }
    }
}

extern "C" void kernel_launch(void* const* d_in, const int* in_sizes, int n_in,
                              void* d_out, int out_size, void* d_ws, size_t ws_size,
                              hipStream_t stream) {
    const float* hs = (const float*)d_in[0];
    const float* wr = (const float*)d_in[1];
    const float* wg = (const float*)d_in[2];
    const float* wu = (const float*)d_in[3];
    const float* wd = (const float*)d_in[4];
    float* out = (float*)d_out;

    int*   cnt   = (int*)d_ws;
    float* probs = (float*)((char*)d_ws + 64);
    int*   ttok  = (int*)((char*)d_ws + 4096);
    float* twt   = (float*)((char*)d_ws + 4096 + sizeof(int)*(size_t)Ee*NTOK);

    // zero output (atomic accumulation target) and ws counters
    hipMemsetAsync(d_out, 0, (size_t)(NTOK*Hh + 1)*sizeof(float), stream);
    hipMemsetAsync(d_ws, 0, 4096, stream);

    router_kernel<<<NTOK/4, 256, 0, stream>>>(hs, wr, cnt, probs, ttok, twt);
    aux_kernel<<<1, 64, 0, stream>>>(cnt, probs, out + (size_t)NTOK*Hh);

    // 1-D grid, expert = wgid&7 (XCD-aligned); 1024 tiles/expert worst case
    int tiles = (NTOK + TT - 1)/TT;
    expert_kernel<<<tiles*Ee, 256, 0, stream>>>(hs, wg, wu, wd, cnt, ttok, twt, out);
}

// Round 3
// 5189.080 us; speedup vs baseline: 3.6544x; 3.6544x over previous
//
#include <hip/hip_runtime.h>
#include <hip/hip_bf16.h>
#include <math.h>

#define Bb 8
#define Ss 4096
#define Hh 512
#define Ii 1024
#define Ee 8
#define NTOK (Bb*Ss)      // 32768 tokens
#define TT 32             // tokens per expert-block tile
#define IC 128            // I-chunk width
#define KS 16             // K slice for LDS staging
#define NBUCKET 64        // spread buckets for prob-sum atomics

// ws layout (bytes):
//   [0,32)            int   cnt[8]
//   [64, 64+2048)     float probs_part[NBUCKET][8]
//   [4096, +1MB)      int   ttok[E*NTOK]
//   [4096+1MB, +1MB)  float twt [E*NTOK]

#define FMA4(acc, s, b) { (acc).x += (s)*(b).x; (acc).y += (s)*(b).y; (acc).z += (s)*(b).z; (acc).w += (s)*(b).w; }

__device__ __forceinline__ float silu_f(float g) {
    return g / (1.0f + expf(-g));
}

// ---------------- Router ----------------
__global__ __launch_bounds__(256) void router_kernel(
    const float* __restrict__ hs, const float* __restrict__ wr,
    int* __restrict__ cnt, float* __restrict__ probs_part,
    int* __restrict__ ttok, float* __restrict__ twt)
{
    __shared__ __align__(16) float swr[Ee*Hh];   // 16KB
    __shared__ float sblk[Ee];
    int tid = threadIdx.x;
    for (int q = tid; q < Ee*Hh/4; q += 256)
        ((float4*)swr)[q] = ((const float4*)wr)[q];
    if (tid < Ee) sblk[tid] = 0.0f;
    __syncthreads();

    int lane = tid & 63;
    int t = blockIdx.x*4 + (tid >> 6);
    const float4* h4 = (const float4*)(hs + (size_t)t*Hh);

    float acc[Ee];
    #pragma unroll
    for (int e = 0; e < Ee; e++) acc[e] = 0.0f;
    #pragma unroll
    for (int r = 0; r < 2; r++) {
        float4 hv = h4[lane + 64*r];
        #pragma unroll
        for (int e = 0; e < Ee; e++) {
            float4 wv = ((const float4*)swr)[e*(Hh/4) + lane + 64*r];
            acc[e] += hv.x*wv.x + hv.y*wv.y + hv.z*wv.z + hv.w*wv.w;
        }
    }
    #pragma unroll
    for (int e = 0; e < Ee; e++) {
        #pragma unroll
        for (int off = 32; off > 0; off >>= 1)
            acc[e] += __shfl_xor(acc[e], off);
    }

    if (lane == 0) {
        // full softmax for aux probs
        float m = acc[0];
        #pragma unroll
        for (int e = 1; e < Ee; e++) m = fmaxf(m, acc[e]);
        float p[Ee], s = 0.0f;
        #pragma unroll
        for (int e = 0; e < Ee; e++) { p[e] = expf(acc[e]-m); s += p[e]; }
        float inv = 1.0f/s;
        #pragma unroll
        for (int e = 0; e < Ee; e++) atomicAdd(&sblk[e], p[e]*inv);

        // top-2 (strict > keeps lowest index on ties, matching lax.top_k)
        int e0 = 0; float v0 = acc[0];
        #pragma unroll
        for (int e = 1; e < Ee; e++) if (acc[e] > v0) { v0 = acc[e]; e0 = e; }
        int e1 = -1; float v1 = -1e30f;
        #pragma unroll
        for (int e = 0; e < Ee; e++) if (e != e0 && acc[e] > v1) { v1 = acc[e]; e1 = e; }
        float r1 = expf(v1 - v0);
        float w0 = 1.0f/(1.0f + r1);
        float w1 = r1*w0;
        int p0 = atomicAdd(&cnt[e0], 1);
        ttok[e0*NTOK + p0] = t; twt[e0*NTOK + p0] = w0;
        int p1 = atomicAdd(&cnt[e1], 1);
        ttok[e1*NTOK + p1] = t; twt[e1*NTOK + p1] = w1;
    }
    __syncthreads();
    if (tid < Ee)
        atomicAdd(&probs_part[(blockIdx.x & (NBUCKET-1))*Ee + tid], sblk[tid]);
}

// ---------------- Aux loss ----------------
__global__ void aux_kernel(const int* __restrict__ cnt,
                           const float* __restrict__ probs_part,
                           float* __restrict__ out_aux)
{
    if (threadIdx.x == 0 && blockIdx.x == 0) {
        float aux = 0.0f;
        for (int e = 0; e < Ee; e++) {
            float ps = 0.0f;
            for (int b = 0; b < NBUCKET; b++) ps += probs_part[b*Ee + e];
            aux += (ps/(float)NTOK) * ((float)cnt[e]/(float)(2*NTOK));
        }
        out_aux[0] = aux * (float)Ee;
    }
}

// ---------------- Fused expert FFN ----------------
// R3 change vs R2: ONLY the occupancy attributes. R2's VGPR_Count=84 proved
// the backend spilled ~140 live floats of accumulators to scratch chasing
// 6 waves/EU (useless: LDS caps at 3 blocks/CU). WRITE_SIZE=50GB was the
// scratch traffic. amdgpu_waves_per_eu(1,3) gives the allocator a 170-VGPR
// budget so acc_out[4][4]+accg/accu stay in registers.
__global__ __launch_bounds__(256)
__attribute__((amdgpu_waves_per_eu(1, 3)))
void expert_kernel(
    const float* __restrict__ hs,
    const float* __restrict__ wg, const float* __restrict__ wu,
    const float* __restrict__ wd,
    const int* __restrict__ cnt, const int* __restrict__ ttok,
    const float* __restrict__ twt,
    float* __restrict__ out)
{
    int e  = blockIdx.x & (Ee-1);      // XCD-aligned expert id
    int bx = blockIdx.x >> 3;          // tile index within expert
    int n = cnt[e];
    int j0 = bx * TT;
    if (j0 >= n) return;

    __shared__ __align__(16) float smem[IC*TT + KS*Hh];  // 16KB act + 32KB stage
    __shared__ int   sm_tok[TT];
    __shared__ float sm_wt[TT];
    float* sm_act = smem;                 // [IC][TT]
    float* sm_hT  = smem + IC*TT;         // [KS][TT]   (phase1, aliases stage)
    float* sm_wgT = smem + IC*TT + KS*TT; // [KS][IC]
    float* sm_wuT = smem + IC*TT + KS*TT + KS*IC; // [KS][IC]
    float* sm_wdT = smem + IC*TT;         // [KS][Hh]   (phase2, aliases stage)

    int tid = threadIdx.x;
    if (tid < TT) {
        int j = j0 + tid;
        int tk; float w;
        if (j < n) { tk = ttok[e*NTOK + j]; w = twt[e*NTOK + j]; }
        else       { tk = ttok[e*NTOK + j0]; w = 0.0f; }   // padded row: weight 0
        sm_tok[tid] = tk; sm_wt[tid] = w;
    }
    __syncthreads();

    const float* wg_e = wg + (size_t)e*Ii*Hh;
    const float* wu_e = wu + (size_t)e*Ii*Hh;
    const float* wd_e = wd + (size_t)e*Hh*Ii;

    int t0 = (tid >> 5) * 4;   // token sub-row, 0..28
    int x0 = (tid & 31) * 4;   // phase1: i base; phase2: h base

    // ---- hoisted staging addresses (constant across chunks/slices) ----
    int t_h = (tid >> 2) & (TT-1);
    int kq  = (tid & 3) << 2;
    const float* hrow_base = hs + (size_t)sm_tok[t_h]*Hh + kq;
    float* sm_hT_st = sm_hT + kq*TT + t_h;           // +c*TT for c=0..3
    int il = tid & 127;
    int kb = (tid >> 7) << 3;                        // 0 or 8
    float* sm_wgT_st = sm_wgT + kb*IC + il;          // +c*IC
    float* sm_wuT_st = sm_wuT + kb*IC + il;
    int hh = tid << 1;
    const float* wd_row0 = wd_e + (size_t)hh*Ii;
    const float* wd_row1 = wd_row0 + Ii;
    float* sm_wdT_st = sm_wdT + hh;                  // +k*Hh (+1 for rr=1)

    float4 acc_out[4][4];      // [tj][j]: h = x0 + 128*j + c  (64 regs, persists)
    #pragma unroll
    for (int a = 0; a < 4; a++)
        #pragma unroll
        for (int b = 0; b < 4; b++)
            acc_out[a][b] = make_float4(0.f, 0.f, 0.f, 0.f);

    for (int ic = 0; ic < Ii; ic += IC) {
        // ---------- phase 1: gate & up ----------
        float4 accg[4], accu[4];
        #pragma unroll
        for (int a = 0; a < 4; a++) { accg[a] = make_float4(0,0,0,0); accu[a] = make_float4(0,0,0,0); }

        const float* hp = hrow_base;
        const float* gp = wg_e + (size_t)(ic + il)*Hh + kb;
        const float* up = wu_e + (size_t)(ic + il)*Hh + kb;

        // prologue: load slice 0 into regs
        float4 hv = make_float4(0,0,0,0), g0, g1, u0, u1;
        if (tid < 128) hv = *(const float4*)hp;
        g0 = *(const float4*)gp;       g1 = *(const float4*)(gp + 4);
        u0 = *(const float4*)up;       u1 = *(const float4*)(up + 4);

        for (int ks = 0; ks < Hh; ks += KS) {
            // write current slice regs -> LDS
            if (tid < 128) {
                sm_hT_st[0*TT] = hv.x; sm_hT_st[1*TT] = hv.y;
                sm_hT_st[2*TT] = hv.z; sm_hT_st[3*TT] = hv.w;
            }
            sm_wgT_st[0*IC] = g0.x; sm_wgT_st[1*IC] = g0.y;
            sm_wgT_st[2*IC] = g0.z; sm_wgT_st[3*IC] = g0.w;
            sm_wgT_st[4*IC] = g1.x; sm_wgT_st[5*IC] = g1.y;
            sm_wgT_st[6*IC] = g1.z; sm_wgT_st[7*IC] = g1.w;
            sm_wuT_st[0*IC] = u0.x; sm_wuT_st[1*IC] = u0.y;
            sm_wuT_st[2*IC] = u0.z; sm_wuT_st[3*IC] = u0.w;
            sm_wuT_st[4*IC] = u1.x; sm_wuT_st[5*IC] = u1.y;
            sm_wuT_st[6*IC] = u1.z; sm_wuT_st[7*IC] = u1.w;
            __syncthreads();

            // prefetch next slice (overlaps FMA below)
            if (ks + KS < Hh) {
                hp += KS; gp += KS; up += KS;
                if (tid < 128) hv = *(const float4*)hp;
                g0 = *(const float4*)gp;   g1 = *(const float4*)(gp + 4);
                u0 = *(const float4*)up;   u1 = *(const float4*)(up + 4);
            }

            #pragma unroll
            for (int k = 0; k < KS; k++) {
                float4 a  = *(const float4*)&sm_hT [k*TT + t0];
                float4 bg = *(const float4*)&sm_wgT[k*IC + x0];
                float4 bu = *(const float4*)&sm_wuT[k*IC + x0];
                FMA4(accg[0], a.x, bg); FMA4(accg[1], a.y, bg);
                FMA4(accg[2], a.z, bg); FMA4(accg[3], a.w, bg);
                FMA4(accu[0], a.x, bu); FMA4(accu[1], a.y, bu);
                FMA4(accu[2], a.z, bu); FMA4(accu[3], a.w, bu);
            }
            __syncthreads();
        }

        // silu(g)*u -> sm_act[i][t]  (b128 stores over t)
        {
            float4 v;
            v.x = silu_f(accg[0].x)*accu[0].x; v.y = silu_f(accg[1].x)*accu[1].x;
            v.z = silu_f(accg[2].x)*accu[2].x; v.w = silu_f(accg[3].x)*accu[3].x;
            *(float4*)&sm_act[(x0+0)*TT + t0] = v;
            v.x = silu_f(accg[0].y)*accu[0].y; v.y = silu_f(accg[1].y)*accu[1].y;
            v.z = silu_f(accg[2].y)*accu[2].y; v.w = silu_f(accg[3].y)*accu[3].y;
            *(float4*)&sm_act[(x0+1)*TT + t0] = v;
            v.x = silu_f(accg[0].z)*accu[0].z; v.y = silu_f(accg[1].z)*accu[1].z;
            v.z = silu_f(accg[2].z)*accu[2].z; v.w = silu_f(accg[3].z)*accu[3].z;
            *(float4*)&sm_act[(x0+2)*TT + t0] = v;
            v.x = silu_f(accg[0].w)*accu[0].w; v.y = silu_f(accg[1].w)*accu[1].w;
            v.z = silu_f(accg[2].w)*accu[2].w; v.w = silu_f(accg[3].w)*accu[3].w;
            *(float4*)&sm_act[(x0+3)*TT + t0] = v;
        }
        __syncthreads();

        // ---------- phase 2: down proj ----------
        float4 c0[2][4];
        {
            const float* s0 = wd_row0 + ic;
            const float* s1 = wd_row1 + ic;
            #pragma unroll
            for (int q = 0; q < 4; q++) {
                c0[0][q] = *(const float4*)(s0 + 4*q);
                c0[1][q] = *(const float4*)(s1 + 4*q);
            }
        }
        for (int ks2 = 0; ks2 < IC; ks2 += KS) {
            // write current slice regs -> LDS transposed [16k][512h]
            #pragma unroll
            for (int rr = 0; rr < 2; rr++) {
                float* st = sm_wdT_st + rr;
                st[ 0*Hh] = c0[rr][0].x; st[ 1*Hh] = c0[rr][0].y;
                st[ 2*Hh] = c0[rr][0].z; st[ 3*Hh] = c0[rr][0].w;
                st[ 4*Hh] = c0[rr][1].x; st[ 5*Hh] = c0[rr][1].y;
                st[ 6*Hh] = c0[rr][1].z; st[ 7*Hh] = c0[rr][1].w;
                st[ 8*Hh] = c0[rr][2].x; st[ 9*Hh] = c0[rr][2].y;
                st[10*Hh] = c0[rr][2].z; st[11*Hh] = c0[rr][2].w;
                st[12*Hh] = c0[rr][3].x; st[13*Hh] = c0[rr][3].y;
                st[14*Hh] = c0[rr][3].z; st[15*Hh] = c0[rr][3].w;
            }
            __syncthreads();

            // prefetch next slice
            if (ks2 + KS < IC) {
                const float* s0 = wd_row0 + ic + ks2 + KS;
                const float* s1 = wd_row1 + ic + ks2 + KS;
                #pragma unroll
                for (int q = 0; q < 4; q++) {
                    c0[0][q] = *(const float4*)(s0 + 4*q);
                    c0[1][q] = *(const float4*)(s1 + 4*q);
                }
            }

            #pragma unroll
            for (int k = 0; k < KS; k++) {
                float4 av = *(const float4*)&sm_act[(ks2+k)*TT + t0];
                #pragma unroll
                for (int j = 0; j < 4; j++) {
                    float4 b = *(const float4*)&sm_wdT[k*Hh + x0 + 128*j];
                    FMA4(acc_out[0][j], av.x, b);
                    FMA4(acc_out[1][j], av.y, b);
                    FMA4(acc_out[2][j], av.z, b);
                    FMA4(acc_out[3][j], av.w, b);
                }
            }
            __syncthreads();
        }
    }

    // ---------- weighted scatter ----------
    #pragma unroll
    for (int tj = 0; tj < 4; tj++) {
        float w = sm_wt[t0 + tj];
        size_t base = (size_t)sm_tok[t0 + tj]*Hh;
        #pragma unroll
        for (int j = 0; j < 4; j++) {
            float4 v = acc_out[tj][j];
            atomicAdd(&out[base + x0 + 128*j + 0], v.x*w);
            atomicAdd(&out[base + x0 + 128*j + 1], v.y*w);
            atomicAdd(&out[base + x0 + 128*j + 2], v.z*w);
            atomicAdd(&out[base + x0 + 128*j + 3], v.w*w);
        }
    }
}

extern "C" void kernel_launch(void* const* d_in, const int* in_sizes, int n_in,
                              void* d_out, int out_size, void* d_ws, size_t ws_size,
                              hipStream_t stream) {
    const float* hs = (const float*)d_in[0];
    const float* wr = (const float*)d_in[1];
    const float* wg = (const float*)d_in[2];
    const float* wu = (const float*)d_in[3];
    const float* wd = (const float*)d_in[4];
    float* out = (float*)d_out;

    int*   cnt   = (int*)d_ws;
    float* probs = (float*)((char*)d_ws + 64);
    int*   ttok  = (int*)((char*)d_ws + 4096);
    float* twt   = (float*)((char*)d_ws + 4096 + sizeof(int)*(size_t)Ee*NTOK);

    // zero output (atomic accumulation target) and ws counters
    hipMemsetAsync(d_out, 0, (size_t)(NTOK*Hh + 1)*sizeof(float), stream);
    hipMemsetAsync(d_ws, 0, 4096, stream);

    router_kernel<<<NTOK/4, 256, 0, stream>>>(hs, wr, cnt, probs, ttok, twt);
    aux_kernel<<<1, 64, 0, stream>>>(cnt, probs, out + (size_t)NTOK*Hh);

    // 1-D grid, expert = wgid&7 (XCD-aligned); 1024 tiles/expert worst case
    int tiles = (NTOK + TT - 1)/TT;
    expert_kernel<<<tiles*Ee, 256, 0, stream>>>(hs, wg, wu, wd, cnt, ttok, twt, out);
}

// Round 5
// 5181.986 us; speedup vs baseline: 3.6594x; 1.0014x over previous
//
#include <hip/hip_runtime.h>
#include <hip/hip_bf16.h>
#include <math.h>

#define Bb 8
#define Ss 4096
#define Hh 512
#define Ii 1024
#define Ee 8
#define NTOK (Bb*Ss)      // 32768 tokens
#define NBUCKET 64

// ---- legacy fp32 path params (fallback) ----
#define TT 32
#define IC 128
#define KS 16

// ---- MFMA path params ----
#define BM 64             // token rows per block
#define BN 256            // K1: 128 g-cols + 128 u-cols ; K2: 256 h-cols
#define BK 32             // k per step
#define LDK 40            // padded LDS row stride (elems) = 80B; +4-chunk XOR swizzle -> 2-way max (free)

typedef short  bf16x8 __attribute__((ext_vector_type(8)));
typedef float  f32x16 __attribute__((ext_vector_type(16)));
#define MFMA32(a,b,c) __builtin_amdgcn_mfma_f32_32x32x16_bf16((a),(b),(c),0,0,0)
#define ZERO16 {0.f,0.f,0.f,0.f,0.f,0.f,0.f,0.f,0.f,0.f,0.f,0.f,0.f,0.f,0.f,0.f}

// ---- ws layout (bytes) ----
#define WS_CNT     0
#define WS_PROBS   64
#define WS_PREFIX  4096
#define WS_TTOK    8192ull
#define WS_TWT     (WS_TTOK + 4ull*Ee*NTOK)
#define WS_PLANES  (WS_TWT + 4ull*Ee*NTOK)
#define HS_N   ((size_t)NTOK*Hh)        // 16,777,216
#define WE_N   ((size_t)Ee*Ii*Hh)       // 4,194,304
#define WS_HS_HI   WS_PLANES
#define WS_HS_LO   (WS_HS_HI + 2ull*HS_N)
#define WS_WG_HI   (WS_HS_LO + 2ull*HS_N)
#define WS_WG_LO   (WS_WG_HI + 2ull*WE_N)
#define WS_WU_HI   (WS_WG_LO + 2ull*WE_N)
#define WS_WU_LO   (WS_WU_HI + 2ull*WE_N)
#define WS_WD_HI   (WS_WU_LO + 2ull*WE_N)
#define WS_WD_LO   (WS_WD_HI + 2ull*WE_N)
#define ACT_ROWS   66560ull             // 65536 + per-expert 64-pad slack
#define WS_ACT_HI  (WS_WD_LO + 2ull*WE_N)
#define WS_ACT_LO  (WS_ACT_HI + 2ull*ACT_ROWS*Ii)
#define WS_NEED    (WS_ACT_LO + 2ull*ACT_ROWS*Ii)   // ~392 MB

#define FMA4(acc, s, b) { (acc).x += (s)*(b).x; (acc).y += (s)*(b).y; (acc).z += (s)*(b).z; (acc).w += (s)*(b).w; }

__device__ __forceinline__ float silu_f(float g) {
    return g / (1.0f + expf(-g));
}

// ---------------- Router ----------------
__global__ __launch_bounds__(256) void router_kernel(
    const float* __restrict__ hs, const float* __restrict__ wr,
    int* __restrict__ cnt, float* __restrict__ probs_part,
    int* __restrict__ ttok, float* __restrict__ twt)
{
    __shared__ __align__(16) float swr[Ee*Hh];
    __shared__ float sblk[Ee];
    int tid = threadIdx.x;
    for (int q = tid; q < Ee*Hh/4; q += 256)
        ((float4*)swr)[q] = ((const float4*)wr)[q];
    if (tid < Ee) sblk[tid] = 0.0f;
    __syncthreads();

    int lane = tid & 63;
    int t = blockIdx.x*4 + (tid >> 6);
    const float4* h4 = (const float4*)(hs + (size_t)t*Hh);

    float acc[Ee];
    #pragma unroll
    for (int e = 0; e < Ee; e++) acc[e] = 0.0f;
    #pragma unroll
    for (int r = 0; r < 2; r++) {
        float4 hv = h4[lane + 64*r];
        #pragma unroll
        for (int e = 0; e < Ee; e++) {
            float4 wv = ((const float4*)swr)[e*(Hh/4) + lane + 64*r];
            acc[e] += hv.x*wv.x + hv.y*wv.y + hv.z*wv.z + hv.w*wv.w;
        }
    }
    #pragma unroll
    for (int e = 0; e < Ee; e++) {
        #pragma unroll
        for (int off = 32; off > 0; off >>= 1)
            acc[e] += __shfl_xor(acc[e], off);
    }

    if (lane == 0) {
        float m = acc[0];
        #pragma unroll
        for (int e = 1; e < Ee; e++) m = fmaxf(m, acc[e]);
        float p[Ee], s = 0.0f;
        #pragma unroll
        for (int e = 0; e < Ee; e++) { p[e] = expf(acc[e]-m); s += p[e]; }
        float inv = 1.0f/s;
        #pragma unroll
        for (int e = 0; e < Ee; e++) atomicAdd(&sblk[e], p[e]*inv);

        // top-2 (strict > keeps lowest index on ties, matching lax.top_k)
        int e0 = 0; float v0 = acc[0];
        #pragma unroll
        for (int e = 1; e < Ee; e++) if (acc[e] > v0) { v0 = acc[e]; e0 = e; }
        int e1 = -1; float v1 = -1e30f;
        #pragma unroll
        for (int e = 0; e < Ee; e++) if (e != e0 && acc[e] > v1) { v1 = acc[e]; e1 = e; }
        float r1 = expf(v1 - v0);
        float w0 = 1.0f/(1.0f + r1);
        float w1 = r1*w0;
        int p0 = atomicAdd(&cnt[e0], 1);
        ttok[e0*NTOK + p0] = t; twt[e0*NTOK + p0] = w0;
        int p1 = atomicAdd(&cnt[e1], 1);
        ttok[e1*NTOK + p1] = t; twt[e1*NTOK + p1] = w1;
    }
    __syncthreads();
    if (tid < Ee)
        atomicAdd(&probs_part[(blockIdx.x & (NBUCKET-1))*Ee + tid], sblk[tid]);
}

// ---------------- Aux loss + padded prefix ----------------
__global__ void aux_kernel(const int* __restrict__ cnt,
                           const float* __restrict__ probs_part,
                           float* __restrict__ out_aux,
                           int* __restrict__ prefix)
{
    if (threadIdx.x == 0 && blockIdx.x == 0) {
        float aux = 0.0f;
        int acc = 0;
        for (int e = 0; e < Ee; e++) {
            float ps = 0.0f;
            for (int b = 0; b < NBUCKET; b++) ps += probs_part[b*Ee + e];
            aux += (ps/(float)NTOK) * ((float)cnt[e]/(float)(2*NTOK));
            prefix[e] = acc;
            acc += ((cnt[e] + 63) >> 6) << 6;   // 64-padded compaction
        }
        out_aux[0] = aux * (float)Ee;
        prefix[8] = acc;
    }
}

// ---------------- f32 -> (hi,lo) bf16 plane split ----------------
__global__ __launch_bounds__(256) void split_kernel(
    const float* __restrict__ src, ushort* __restrict__ hi, ushort* __restrict__ lo, int n4)
{
    int idx = blockIdx.x*256 + threadIdx.x;
    if (idx >= n4) return;
    float4 f = ((const float4*)src)[idx];
    ushort h[4], l[4];
    #pragma unroll
    for (int j = 0; j < 4; j++) {
        float fv = ((const float*)&f)[j];
        unsigned u = __float_as_uint(fv);
        unsigned r = (u + 0x7fffu + ((u>>16)&1u)) & 0xffff0000u;   // RNE bf16
        h[j] = (ushort)(r >> 16);
        float lof = fv - __uint_as_float(r);                        // exact residual
        l[j] = (ushort)(__float_as_uint(lof) >> 16);                // truncated lo
    }
    ((ushort4*)hi)[idx] = make_ushort4(h[0], h[1], h[2], h[3]);
    ((ushort4*)lo)[idx] = make_ushort4(l[0], l[1], l[2], l[3]);
}

// ---------------- K1: gate/up GEMM + silu*mul -> act planes ----------------
// Block = (expert, 64-token tile, 128-wide i-chunk). Tile 64m x (128g+128u).
// Frags 32x32x16; split-bf16 3-MFMA per operand pair. k packed with identical
// bijection on A and B so the HW's internal k order cancels. C/D mapping:
// col=lane&31, row=(reg&3)+8*(reg>>2)+4*(lane>>5)  [verified m74/m101].
// LDS: LDK=40 stride + 4-chunk XOR swizzle (chunk ^= (row>>3)&3) -> reads
// 2-way max (free, m136), stores conflict-free.
__global__ __launch_bounds__(256)
__attribute__((amdgpu_waves_per_eu(1, 2)))
void gemm1_kernel(const ushort* __restrict__ hs_hi, const ushort* __restrict__ hs_lo,
                  const ushort* __restrict__ wg_hi, const ushort* __restrict__ wg_lo,
                  const ushort* __restrict__ wu_hi, const ushort* __restrict__ wu_lo,
                  const int* __restrict__ cnt, const int* __restrict__ prefix,
                  const int* __restrict__ ttok,
                  ushort* __restrict__ act_hi, ushort* __restrict__ act_lo)
{
    const int e  = blockIdx.x & 7;          // XCD-aligned expert
    const int rr = blockIdx.x >> 3;
    const int mt = rr & 511;
    const int it = rr >> 9;                 // 0..7 i-chunk
    const int n  = cnt[e];
    const int j0 = mt * BM;
    if (j0 >= n) return;
    const int abase = prefix[e] + j0;
    const int ic = it * 128;

    __shared__ __align__(16) ushort sA[2][BM*LDK];   // hi,lo planes
    __shared__ __align__(16) ushort sB[2][BN*LDK];
    __shared__ int sm_tok[BM];

    const int tid = threadIdx.x;
    if (tid < BM) {
        int j = j0 + tid;
        sm_tok[tid] = ttok[e*NTOK + (j < n ? j : j0)];
    }
    __syncthreads();

    // staging: thread -> (row, 16B chunk); swizzled chunk = sch ^ ((srow>>3)&3)
    const int srow = tid >> 2;
    const int sch  = tid & 3;
    const int sxch = (sch ^ ((srow >> 3) & 3)) * 8;
    const ushort* aph = hs_hi + (size_t)sm_tok[srow]*Hh + sch*8;
    const ushort* apl = hs_lo + (size_t)sm_tok[srow]*Hh + sch*8;
    const int a_st = srow*LDK + sxch;

    const ushort* wgh_e = wg_hi + (size_t)e*Ii*Hh;
    const ushort* wgl_e = wg_lo + (size_t)e*Ii*Hh;
    const ushort* wuh_e = wu_hi + (size_t)e*Ii*Hh;
    const ushort* wul_e = wu_lo + (size_t)e*Ii*Hh;
    const ushort* bph[4];
    const ushort* bpl[4];
    bph[0] = wgh_e + (size_t)(ic +      srow)*Hh + sch*8;
    bpl[0] = wgl_e + (size_t)(ic +      srow)*Hh + sch*8;
    bph[1] = wgh_e + (size_t)(ic + 64 + srow)*Hh + sch*8;
    bpl[1] = wgl_e + (size_t)(ic + 64 + srow)*Hh + sch*8;
    bph[2] = wuh_e + (size_t)(ic +      srow)*Hh + sch*8;
    bpl[2] = wul_e + (size_t)(ic +      srow)*Hh + sch*8;
    bph[3] = wuh_e + (size_t)(ic + 64 + srow)*Hh + sch*8;
    bpl[3] = wul_e + (size_t)(ic + 64 + srow)*Hh + sch*8;
    int b_st[4];
    #pragma unroll
    for (int c = 0; c < 4; c++) b_st[c] = (c*64 + srow)*LDK + sxch;  // (row>>3)&3 invariant under +64

    // frag read offsets; swizzled chunk(kk) = (2*kk+g) ^ axr
    const int w   = tid >> 6;
    const int l31 = tid & 31;
    const int g   = (tid >> 5) & 1;
    const int axr = (l31 >> 3) & 3;          // rows differ by mult of 32 -> same axr
    const int ck0 = ((g    ) ^ axr) * 8;     // kk=0
    const int ck1 = ((g + 2) ^ axr) * 8;     // kk=1
    const int arow0 = (     l31)*LDK;
    const int arow1 = (32 + l31)*LDK;
    const int brow_g = ((w  )*32 + l31)*LDK;
    const int brow_u = ((w+4)*32 + l31)*LDK;

    f32x16 accg0 = ZERO16, accg1 = ZERO16, accu0 = ZERO16, accu1 = ZERO16;

    // prologue loads (step 0)
    bf16x8 ra_h = *(const bf16x8*)aph;
    bf16x8 ra_l = *(const bf16x8*)apl;
    bf16x8 rb_h[4], rb_l[4];
    #pragma unroll
    for (int c = 0; c < 4; c++) { rb_h[c] = *(const bf16x8*)bph[c]; rb_l[c] = *(const bf16x8*)bpl[c]; }

    for (int ks = 0; ks < Hh/BK; ks++) {
        *(bf16x8*)&sA[0][a_st] = ra_h;
        *(bf16x8*)&sA[1][a_st] = ra_l;
        #pragma unroll
        for (int c = 0; c < 4; c++) {
            *(bf16x8*)&sB[0][b_st[c]] = rb_h[c];
            *(bf16x8*)&sB[1][b_st[c]] = rb_l[c];
        }
        __syncthreads();

        if (ks + 1 < Hh/BK) {                 // prefetch next slice under MFMA
            aph += BK; apl += BK;
            ra_h = *(const bf16x8*)aph; ra_l = *(const bf16x8*)apl;
            #pragma unroll
            for (int c = 0; c < 4; c++) {
                bph[c] += BK; bpl[c] += BK;
                rb_h[c] = *(const bf16x8*)bph[c];
                rb_l[c] = *(const bf16x8*)bpl[c];
            }
        }

        #pragma unroll
        for (int kk = 0; kk < 2; kk++) {
            const int ck = kk ? ck1 : ck0;
            bf16x8 a0h = *(const bf16x8*)&sA[0][arow0 + ck];
            bf16x8 a0l = *(const bf16x8*)&sA[1][arow0 + ck];
            bf16x8 a1h = *(const bf16x8*)&sA[0][arow1 + ck];
            bf16x8 a1l = *(const bf16x8*)&sA[1][arow1 + ck];
            bf16x8 bgh = *(const bf16x8*)&sB[0][brow_g + ck];
            bf16x8 bgl = *(const bf16x8*)&sB[1][brow_g + ck];
            bf16x8 buh = *(const bf16x8*)&sB[0][brow_u + ck];
            bf16x8 bul = *(const bf16x8*)&sB[1][brow_u + ck];
            accg0 = MFMA32(a0h, bgh, accg0);
            accg0 = MFMA32(a0l, bgh, accg0);
            accg0 = MFMA32(a0h, bgl, accg0);
            accu0 = MFMA32(a0h, buh, accu0);
            accu0 = MFMA32(a0l, buh, accu0);
            accu0 = MFMA32(a0h, bul, accu0);
            accg1 = MFMA32(a1h, bgh, accg1);
            accg1 = MFMA32(a1l, bgh, accg1);
            accg1 = MFMA32(a1h, bgl, accg1);
            accu1 = MFMA32(a1h, buh, accu1);
            accu1 = MFMA32(a1l, buh, accu1);
            accu1 = MFMA32(a1h, bul, accu1);
        }
        __syncthreads();
    }

    // epilogue: act = silu(g)*u, split hi/lo, store compact rows
    const int icol = ic + w*32 + l31;
    #pragma unroll
    for (int r = 0; r < 16; r++) {
        int m = (r&3) + 8*(r>>2) + 4*g;
        {
            float a = silu_f(accg0[r]) * accu0[r];
            size_t off = (size_t)(abase + m)*Ii + icol;
            unsigned u = __float_as_uint(a);
            unsigned rh = (u + 0x7fffu + ((u>>16)&1u)) & 0xffff0000u;
            act_hi[off] = (ushort)(rh >> 16);
            float lof = a - __uint_as_float(rh);
            act_lo[off] = (ushort)(__float_as_uint(lof) >> 16);
        }
        {
            float a = silu_f(accg1[r]) * accu1[r];
            size_t off = (size_t)(abase + 32 + m)*Ii + icol;
            unsigned u = __float_as_uint(a);
            unsigned rh = (u + 0x7fffu + ((u>>16)&1u)) & 0xffff0000u;
            act_hi[off] = (ushort)(rh >> 16);
            float lof = a - __uint_as_float(rh);
            act_lo[off] = (ushort)(__float_as_uint(lof) >> 16);
        }
    }
}

// ---------------- K2: down-proj GEMM + weighted atomic scatter ----------------
__global__ __launch_bounds__(256)
__attribute__((amdgpu_waves_per_eu(1, 2)))
void gemm2_kernel(const ushort* __restrict__ act_hi, const ushort* __restrict__ act_lo,
                  const ushort* __restrict__ wd_hi, const ushort* __restrict__ wd_lo,
                  const int* __restrict__ cnt, const int* __restrict__ prefix,
                  const int* __restrict__ ttok, const float* __restrict__ twt,
                  float* __restrict__ out)
{
    const int e  = blockIdx.x & 7;
    const int rr = blockIdx.x >> 3;
    const int mt = rr & 511;
    const int ht = rr >> 9;                 // 0..1 h half
    const int n  = cnt[e];
    const int j0 = mt * BM;
    if (j0 >= n) return;
    const int abase = prefix[e] + j0;
    const int hbase = ht * 256;

    __shared__ __align__(16) ushort sA[2][BM*LDK];
    __shared__ __align__(16) ushort sB[2][BN*LDK];
    __shared__ int   sm_tok[BM];
    __shared__ float sm_wt[BM];

    const int tid = threadIdx.x;
    if (tid < BM) {
        int j = j0 + tid;
        if (j < n) { sm_tok[tid] = ttok[e*NTOK + j]; sm_wt[tid] = twt[e*NTOK + j]; }
        else       { sm_tok[tid] = ttok[e*NTOK + j0]; sm_wt[tid] = 0.0f; }
    }
    __syncthreads();

    const int srow = tid >> 2;
    const int sch  = tid & 3;
    const int sxch = (sch ^ ((srow >> 3) & 3)) * 8;
    const ushort* aph = act_hi + (size_t)(abase + srow)*Ii + sch*8;
    const ushort* apl = act_lo + (size_t)(abase + srow)*Ii + sch*8;
    const int a_st = srow*LDK + sxch;

    const ushort* wdh_e = wd_hi + (size_t)e*Hh*Ii;
    const ushort* wdl_e = wd_lo + (size_t)e*Hh*Ii;
    const ushort* bph[4];
    const ushort* bpl[4];
    #pragma unroll
    for (int c = 0; c < 4; c++) {
        bph[c] = wdh_e + (size_t)(hbase + c*64 + srow)*Ii + sch*8;
        bpl[c] = wdl_e + (size_t)(hbase + c*64 + srow)*Ii + sch*8;
    }
    int b_st[4];
    #pragma unroll
    for (int c = 0; c < 4; c++) b_st[c] = (c*64 + srow)*LDK + sxch;

    const int w   = tid >> 6;
    const int l31 = tid & 31;
    const int g   = (tid >> 5) & 1;
    const int axr = (l31 >> 3) & 3;
    const int ck0 = ((g    ) ^ axr) * 8;
    const int ck1 = ((g + 2) ^ axr) * 8;
    const int arow0 = (     l31)*LDK;
    const int arow1 = (32 + l31)*LDK;
    const int brow_a = ((w  )*32 + l31)*LDK;
    const int brow_b = ((w+4)*32 + l31)*LDK;

    f32x16 acc00 = ZERO16, acc01 = ZERO16, acc10 = ZERO16, acc11 = ZERO16;

    bf16x8 ra_h = *(const bf16x8*)aph;
    bf16x8 ra_l = *(const bf16x8*)apl;
    bf16x8 rb_h[4], rb_l[4];
    #pragma unroll
    for (int c = 0; c < 4; c++) { rb_h[c] = *(const bf16x8*)bph[c]; rb_l[c] = *(const bf16x8*)bpl[c]; }

    for (int ks = 0; ks < Ii/BK; ks++) {
        *(bf16x8*)&sA[0][a_st] = ra_h;
        *(bf16x8*)&sA[1][a_st] = ra_l;
        #pragma unroll
        for (int c = 0; c < 4; c++) {
            *(bf16x8*)&sB[0][b_st[c]] = rb_h[c];
            *(bf16x8*)&sB[1][b_st[c]] = rb_l[c];
        }
        __syncthreads();

        if (ks + 1 < Ii/BK) {
            aph += BK; apl += BK;
            ra_h = *(const bf16x8*)aph; ra_l = *(const bf16x8*)apl;
            #pragma unroll
            for (int c = 0; c < 4; c++) {
                bph[c] += BK; bpl[c] += BK;
                rb_h[c] = *(const bf16x8*)bph[c];
                rb_l[c] = *(const bf16x8*)bpl[c];
            }
        }

        #pragma unroll
        for (int kk = 0; kk < 2; kk++) {
            const int ck = kk ? ck1 : ck0;
            bf16x8 a0h = *(const bf16x8*)&sA[0][arow0 + ck];
            bf16x8 a0l = *(const bf16x8*)&sA[1][arow0 + ck];
            bf16x8 a1h = *(const bf16x8*)&sA[0][arow1 + ck];
            bf16x8 a1l = *(const bf16x8*)&sA[1][arow1 + ck];
            bf16x8 b0h = *(const bf16x8*)&sB[0][brow_a + ck];
            bf16x8 b0l = *(const bf16x8*)&sB[1][brow_a + ck];
            bf16x8 b1h = *(const bf16x8*)&sB[0][brow_b + ck];
            bf16x8 b1l = *(const bf16x8*)&sB[1][brow_b + ck];
            acc00 = MFMA32(a0h, b0h, acc00);
            acc00 = MFMA32(a0l, b0h, acc00);
            acc00 = MFMA32(a0h, b0l, acc00);
            acc01 = MFMA32(a0h, b1h, acc01);
            acc01 = MFMA32(a0l, b1h, acc01);
            acc01 = MFMA32(a0h, b1l, acc01);
            acc10 = MFMA32(a1h, b0h, acc10);
            acc10 = MFMA32(a1l, b0h, acc10);
            acc10 = MFMA32(a1h, b0l, acc10);
            acc11 = MFMA32(a1h, b1h, acc11);
            acc11 = MFMA32(a1l, b1h, acc11);
            acc11 = MFMA32(a1h, b1l, acc11);
        }
        __syncthreads();
    }

    // weighted scatter
    const int h0 = hbase +       w*32 + l31;
    const int h1 = hbase + 128 + w*32 + l31;
    #pragma unroll
    for (int r = 0; r < 16; r++) {
        int m = (r&3) + 8*(r>>2) + 4*g;
        int   tok0 = sm_tok[m],      tok1 = sm_tok[32 + m];
        float wt0  = sm_wt[m],       wt1  = sm_wt[32 + m];
        atomicAdd(&out[(size_t)tok0*Hh + h0], acc00[r]*wt0);
        atomicAdd(&out[(size_t)tok0*Hh + h1], acc01[r]*wt0);
        atomicAdd(&out[(size_t)tok1*Hh + h0], acc10[r]*wt1);
        atomicAdd(&out[(size_t)tok1*Hh + h1], acc11[r]*wt1);
    }
}

// ---------------- Fallback: R3 fp32 expert kernel (used when ws too small) ----------------
__global__ __launch_bounds__(256)
__attribute__((amdgpu_waves_per_eu(1, 3)))
void expert_kernel(
    const float* __restrict__ hs,
    const float* __restrict__ wg, const float* __restrict__ wu,
    const float* __restrict__ wd,
    const int* __restrict__ cnt, const int* __restrict__ ttok,
    const float* __restrict__ twt,
    float* __restrict__ out)
{
    int e  = blockIdx.x & (Ee-1);
    int bx = blockIdx.x >> 3;
    int n = cnt[e];
    int j0 = bx * TT;
    if (j0 >= n) return;

    __shared__ __align__(16) float smem[IC*TT + KS*Hh];
    __shared__ int   sm_tok[TT];
    __shared__ float sm_wt[TT];
    float* sm_act = smem;
    float* sm_hT  = smem + IC*TT;
    float* sm_wgT = smem + IC*TT + KS*TT;
    float* sm_wuT = smem + IC*TT + KS*TT + KS*IC;
    float* sm_wdT = smem + IC*TT;

    int tid = threadIdx.x;
    if (tid < TT) {
        int j = j0 + tid;
        int tk; float w;
        if (j < n) { tk = ttok[e*NTOK + j]; w = twt[e*NTOK + j]; }
        else       { tk = ttok[e*NTOK + j0]; w = 0.0f; }
        sm_tok[tid] = tk; sm_wt[tid] = w;
    }
    __syncthreads();

    const float* wg_e = wg + (size_t)e*Ii*Hh;
    const float* wu_e = wu + (size_t)e*Ii*Hh;
    const float* wd_e = wd + (size_t)e*Hh*Ii;

    int t0 = (tid >> 5) * 4;
    int x0 = (tid & 31) * 4;

    int t_h = (tid >> 2) & (TT-1);
    int kq  = (tid & 3) << 2;
    const float* hrow_base = hs + (size_t)sm_tok[t_h]*Hh + kq;
    float* sm_hT_st = sm_hT + kq*TT + t_h;
    int il = tid & 127;
    int kb = (tid >> 7) << 3;
    float* sm_wgT_st = sm_wgT + kb*IC + il;
    float* sm_wuT_st = sm_wuT + kb*IC + il;
    int hh = tid << 1;
    const float* wd_row0 = wd_e + (size_t)hh*Ii;
    const float* wd_row1 = wd_row0 + Ii;
    float* sm_wdT_st = sm_wdT + hh;

    float4 acc_out[4][4];
    #pragma unroll
    for (int a = 0; a < 4; a++)
        #pragma unroll
        for (int b = 0; b < 4; b++)
            acc_out[a][b] = make_float4(0.f, 0.f, 0.f, 0.f);

    for (int ic = 0; ic < Ii; ic += IC) {
        float4 accg[4], accu[4];
        #pragma unroll
        for (int a = 0; a < 4; a++) { accg[a] = make_float4(0,0,0,0); accu[a] = make_float4(0,0,0,0); }

        const float* hp = hrow_base;
        const float* gp = wg_e + (size_t)(ic + il)*Hh + kb;
        const float* up = wu_e + (size_t)(ic + il)*Hh + kb;

        float4 hv = make_float4(0,0,0,0), g0, g1, u0, u1;
        if (tid < 128) hv = *(const float4*)hp;
        g0 = *(const float4*)gp;       g1 = *(const float4*)(gp + 4);
        u0 = *(const float4*)up;       u1 = *(const float4*)(up + 4);

        for (int ks = 0; ks < Hh; ks += KS) {
            if (tid < 128) {
                sm_hT_st[0*TT] = hv.x; sm_hT_st[1*TT] = hv.y;
                sm_hT_st[2*TT] = hv.z; sm_hT_st[3*TT] = hv.w;
            }
            sm_wgT_st[0*IC] = g0.x; sm_wgT_st[1*IC] = g0.y;
            sm_wgT_st[2*IC] = g0.z; sm_wgT_st[3*IC] = g0.w;
            sm_wgT_st[4*IC] = g1.x; sm_wgT_st[5*IC] = g1.y;
            sm_wgT_st[6*IC] = g1.z; sm_wgT_st[7*IC] = g1.w;
            sm_wuT_st[0*IC] = u0.x; sm_wuT_st[1*IC] = u0.y;
            sm_wuT_st[2*IC] = u0.z; sm_wuT_st[3*IC] = u0.w;
            sm_wuT_st[4*IC] = u1.x; sm_wuT_st[5*IC] = u1.y;
            sm_wuT_st[6*IC] = u1.z; sm_wuT_st[7*IC] = u1.w;
            __syncthreads();

            if (ks + KS < Hh) {
                hp += KS; gp += KS; up += KS;
                if (tid < 128) hv = *(const float4*)hp;
                g0 = *(const float4*)gp;   g1 = *(const float4*)(gp + 4);
                u0 = *(const float4*)up;   u1 = *(const float4*)(up + 4);
            }

            #pragma unroll
            for (int k = 0; k < KS; k++) {
                float4 a  = *(const float4*)&sm_hT [k*TT + t0];
                float4 bg = *(const float4*)&sm_wgT[k*IC + x0];
                float4 bu = *(const float4*)&sm_wuT[k*IC + x0];
                FMA4(accg[0], a.x, bg); FMA4(accg[1], a.y, bg);
                FMA4(accg[2], a.z, bg); FMA4(accg[3], a.w, bg);
                FMA4(accu[0], a.x, bu); FMA4(accu[1], a.y, bu);
                FMA4(accu[2], a.z, bu); FMA4(accu[3], a.w, bu);
            }
            __syncthreads();
        }

        {
            float4 v;
            v.x = silu_f(accg[0].x)*accu[0].x; v.y = silu_f(accg[1].x)*accu[1].x;
            v.z = silu_f(accg[2].x)*accu[2].x; v.w = silu_f(accg[3].x)*accu[3].x;
            *(float4*)&sm_act[(x0+0)*TT + t0] = v;
            v.x = silu_f(accg[0].y)*accu[0].y; v.y = silu_f(accg[1].y)*accu[1].y;
            v.z = silu_f(accg[2].y)*accu[2].y; v.w = silu_f(accg[3].y)*accu[3].y;
            *(float4*)&sm_act[(x0+1)*TT + t0] = v;
            v.x = silu_f(accg[0].z)*accu[0].z; v.y = silu_f(accg[1].z)*accu[1].z;
            v.z = silu_f(accg[2].z)*accu[2].z; v.w = silu_f(accg[3].z)*accu[3].z;
            *(float4*)&sm_act[(x0+2)*TT + t0] = v;
            v.x = silu_f(accg[0].w)*accu[0].w; v.y = silu_f(accg[1].w)*accu[1].w;
            v.z = silu_f(accg[2].w)*accu[2].w; v.w = silu_f(accg[3].w)*accu[3].w;
            *(float4*)&sm_act[(x0+3)*TT + t0] = v;
        }
        __syncthreads();

        float4 c0[2][4];
        {
            const float* s0 = wd_row0 + ic;
            const float* s1 = wd_row1 + ic;
            #pragma unroll
            for (int q = 0; q < 4; q++) {
                c0[0][q] = *(const float4*)(s0 + 4*q);
                c0[1][q] = *(const float4*)(s1 + 4*q);
            }
        }
        for (int ks2 = 0; ks2 < IC; ks2 += KS) {
            #pragma unroll
            for (int rr2 = 0; rr2 < 2; rr2++) {
                float* st = sm_wdT_st + rr2;
                st[ 0*Hh] = c0[rr2][0].x; st[ 1*Hh] = c0[rr2][0].y;
                st[ 2*Hh] = c0[rr2][0].z; st[ 3*Hh] = c0[rr2][0].w;
                st[ 4*Hh] = c0[rr2][1].x; st[ 5*Hh] = c0[rr2][1].y;
                st[ 6*Hh] = c0[rr2][1].z; st[ 7*Hh] = c0[rr2][1].w;
                st[ 8*Hh] = c0[rr2][2].x; st[ 9*Hh] = c0[rr2][2].y;
                st[10*Hh] = c0[rr2][2].z; st[11*Hh] = c0[rr2][2].w;
                st[12*Hh] = c0[rr2][3].x; st[13*Hh] = c0[rr2][3].y;
                st[14*Hh] = c0[rr2][3].z; st[15*Hh] = c0[rr2][3].w;
            }
            __syncthreads();

            if (ks2 + KS < IC) {
                const float* s0 = wd_row0 + ic + ks2 + KS;
                const float* s1 = wd_row1 + ic + ks2 + KS;
                #pragma unroll
                for (int q = 0; q < 4; q++) {
                    c0[0][q] = *(const float4*)(s0 + 4*q);
                    c0[1][q] = *(const float4*)(s1 + 4*q);
                }
            }

            #pragma unroll
            for (int k = 0; k < KS; k++) {
                float4 av = *(const float4*)&sm_act[(ks2+k)*TT + t0];
                #pragma unroll
                for (int j = 0; j < 4; j++) {
                    float4 b = *(const float4*)&sm_wdT[k*Hh + x0 + 128*j];
                    FMA4(acc_out[0][j], av.x, b);
                    FMA4(acc_out[1][j], av.y, b);
                    FMA4(acc_out[2][j], av.z, b);
                    FMA4(acc_out[3][j], av.w, b);
                }
            }
            __syncthreads();
        }
    }

    #pragma unroll
    for (int tj = 0; tj < 4; tj++) {
        float w = sm_wt[t0 + tj];
        size_t base = (size_t)sm_tok[t0 + tj]*Hh;
        #pragma unroll
        for (int j = 0; j < 4; j++) {
            float4 v = acc_out[tj][j];
            atomicAdd(&out[base + x0 + 128*j + 0], v.x*w);
            atomicAdd(&out[base + x0 + 128*j + 1], v.y*w);
            atomicAdd(&out[base + x0 + 128*j + 2], v.z*w);
            atomicAdd(&out[base + x0 + 128*j + 3], v.w*w);
        }
    }
}

extern "C" void kernel_launch(void* const* d_in, const int* in_sizes, int n_in,
                              void* d_out, int out_size, void* d_ws, size_t ws_size,
                              hipStream_t stream) {
    const float* hs = (const float*)d_in[0];
    const float* wr = (const float*)d_in[1];
    const float* wg = (const float*)d_in[2];
    const float* wu = (const float*)d_in[3];
    const float* wd = (const float*)d_in[4];
    float* out = (float*)d_out;

    char* ws = (char*)d_ws;
    int*   cnt    = (int*)(ws + WS_CNT);
    float* probs  = (float*)(ws + WS_PROBS);
    int*   prefix = (int*)(ws + WS_PREFIX);
    int*   ttok   = (int*)(ws + WS_TTOK);
    float* twt    = (float*)(ws + WS_TWT);

    hipMemsetAsync(d_out, 0, ((size_t)NTOK*Hh + 1)*sizeof(float), stream);
    hipMemsetAsync(d_ws, 0, 4608, stream);

    router_kernel<<<NTOK/4, 256, 0, stream>>>(hs, wr, cnt, probs, ttok, twt);
    aux_kernel<<<1, 64, 0, stream>>>(cnt, probs, out + (size_t)NTOK*Hh, prefix);

    if (ws_size >= WS_NEED) {
        ushort* hs_hi = (ushort*)(ws + WS_HS_HI);
        ushort* hs_lo = (ushort*)(ws + WS_HS_LO);
        ushort* wg_hi = (ushort*)(ws + WS_WG_HI);
        ushort* wg_lo = (ushort*)(ws + WS_WG_LO);
        ushort* wu_hi = (ushort*)(ws + WS_WU_HI);
        ushort* wu_lo = (ushort*)(ws + WS_WU_LO);
        ushort* wd_hi = (ushort*)(ws + WS_WD_HI);
        ushort* wd_lo = (ushort*)(ws + WS_WD_LO);
        ushort* act_hi = (ushort*)(ws + WS_ACT_HI);
        ushort* act_lo = (ushort*)(ws + WS_ACT_LO);

        split_kernel<<<(int)(HS_N/4/256), 256, 0, stream>>>(hs, hs_hi, hs_lo, (int)(HS_N/4));
        split_kernel<<<(int)(WE_N/4/256), 256, 0, stream>>>(wg, wg_hi, wg_lo, (int)(WE_N/4));
        split_kernel<<<(int)(WE_N/4/256), 256, 0, stream>>>(wu, wu_hi, wu_lo, (int)(WE_N/4));
        split_kernel<<<(int)(WE_N/4/256), 256, 0, stream>>>(wd, wd_hi, wd_lo, (int)(WE_N/4));

        gemm1_kernel<<<8*512*8, 256, 0, stream>>>(hs_hi, hs_lo, wg_hi, wg_lo, wu_hi, wu_lo,
                                                  cnt, prefix, ttok, act_hi, act_lo);
        gemm2_kernel<<<8*512*2, 256, 0, stream>>>(act_hi, act_lo, wd_hi, wd_lo,
                                                  cnt, prefix, ttok, twt, out);
    } else {
        expert_kernel<<<1024*8, 256, 0, stream>>>(hs, wg, wu, wd, cnt, ttok, twt, out);
    }
}